// Round 1
// baseline (372.235 us; speedup 1.0000x reference)
//
#include <hip/hip_runtime.h>
#include <math.h>

// Problem constants (shape (8,1,32,256,256) f32)
#define N_BATCH 8
#define DEPTH   32
#define HEIGHT  256
#define WIDTH   256
#define WZ 5
#define WYT 11
#define WXT 11
#define RZ 2
#define RY 5
#define RX 5

#define TY 32
#define TX 32
#define HY (TY + WYT - 1)   // 42
#define HX (TX + WXT - 1)   // 42

#define COUNT 16777216.0    // 8*32*256*256

struct Weights {
    float wz[WZ];
    float wy[WYT];
    float wx[WXT];
};

__global__ __launch_bounds__(256) void ssim3d_fused(
    const float* __restrict__ img1, const float* __restrict__ img2,
    double* __restrict__ acc, Weights W)
{
    // block id -> (n, z_out, tile_y, tile_x)
    int bid = blockIdx.x;
    const int tiles_x = WIDTH / TX;   // 8
    const int tiles_y = HEIGHT / TY;  // 8
    int txi = bid % tiles_x; bid /= tiles_x;
    int tyi = bid % tiles_y; bid /= tiles_y;
    int z_out = bid % DEPTH; bid /= DEPTH;
    int n = bid;

    const int y0 = tyi * TY - RY;  // halo origin (may be negative)
    const int x0 = txi * TX - RX;

    __shared__ float facc[5][HY][HX];   // 35.3 KiB  z-convolved fields
    __shared__ float tmp[5][TY][HX];    // 26.9 KiB  +y-convolved
    __shared__ float wred[4];

    const int tid = threadIdx.x;
    const int NPOS = HY * HX;   // 1764

    // per-thread z-accumulators: up to 7 halo positions, 5 fields.
    // Fully unrolled so indices are compile-time (no scratch).
    float a0[7][5];
#pragma unroll
    for (int p = 0; p < 7; ++p)
#pragma unroll
        for (int f = 0; f < 5; ++f) a0[p][f] = 0.f;

    const size_t base_n = (size_t)n * DEPTH * HEIGHT * WIDTH;

    for (int kz = 0; kz < WZ; ++kz) {
        int z_in = z_out + kz - RZ;
        if (z_in < 0 || z_in >= DEPTH) continue;  // zero padding
        const float wzv = W.wz[kz];
        const float* p1 = img1 + base_n + (size_t)z_in * HEIGHT * WIDTH;
        const float* p2 = img2 + base_n + (size_t)z_in * HEIGHT * WIDTH;
#pragma unroll
        for (int pi = 0; pi < 7; ++pi) {
            int pos = tid + pi * 256;
            if (pos < NPOS) {
                int hy = pos / HX, hx = pos - hy * HX;
                int gy = y0 + hy, gx = x0 + hx;
                float a = 0.f, b = 0.f;
                if (gy >= 0 && gy < HEIGHT && gx >= 0 && gx < WIDTH) {
                    int off = gy * WIDTH + gx;
                    a = p1[off];
                    b = p2[off];
                }
                a0[pi][0] += wzv * a;
                a0[pi][1] += wzv * b;
                a0[pi][2] += wzv * (a * a);
                a0[pi][3] += wzv * (b * b);
                a0[pi][4] += wzv * (a * b);
            }
        }
    }

    // registers -> LDS
#pragma unroll
    for (int pi = 0; pi < 7; ++pi) {
        int pos = tid + pi * 256;
        if (pos < NPOS) {
            int hy = pos / HX, hx = pos - hy * HX;
#pragma unroll
            for (int f = 0; f < 5; ++f) facc[f][hy][hx] = a0[pi][f];
        }
    }
    __syncthreads();

    // y-conv: tmp[f][y][x] = sum_j wy[j] * facc[f][y+j][x]
    const int NT = TY * HX;  // 1344
    for (int pos = tid; pos < NT; pos += 256) {
        int y = pos / HX, x = pos - (pos / HX) * HX;
        float s0 = 0.f, s1 = 0.f, s2 = 0.f, s3 = 0.f, s4 = 0.f;
#pragma unroll
        for (int j = 0; j < WYT; ++j) {
            float w = W.wy[j];
            s0 += w * facc[0][y + j][x];
            s1 += w * facc[1][y + j][x];
            s2 += w * facc[2][y + j][x];
            s3 += w * facc[3][y + j][x];
            s4 += w * facc[4][y + j][x];
        }
        tmp[0][y][x] = s0;
        tmp[1][y][x] = s1;
        tmp[2][y][x] = s2;
        tmp[3][y][x] = s3;
        tmp[4][y][x] = s4;
    }
    __syncthreads();

    // x-conv + SSIM map + accumulate
    float lsum = 0.f;
    const float C1 = 0.0001f;   // (1.0*0.01)^2
    const float C2 = 0.0009f;   // (1.0*0.03)^2
#pragma unroll
    for (int pi = 0; pi < 4; ++pi) {
        int pos = tid + pi * 256;   // < 1024 always
        int y = pos >> 5, x = pos & 31;
        float s0 = 0.f, s1 = 0.f, s2 = 0.f, s3 = 0.f, s4 = 0.f;
#pragma unroll
        for (int j = 0; j < WXT; ++j) {
            float w = W.wx[j];
            s0 += w * tmp[0][y][x + j];
            s1 += w * tmp[1][y][x + j];
            s2 += w * tmp[2][y][x + j];
            s3 += w * tmp[3][y][x + j];
            s4 += w * tmp[4][y][x + j];
        }
        float mu1 = s0, mu2 = s1;
        float mu1_sq = mu1 * mu1;
        float mu2_sq = mu2 * mu2;
        float mu1_mu2 = mu1 * mu2;
        float sig1 = s2 - mu1_sq;
        float sig2 = s3 - mu2_sq;
        float sig12 = s4 - mu1_mu2;
        float num = (2.f * mu1_mu2 + C1) * (2.f * sig12 + C2);
        float den = (mu1_sq + mu2_sq + C1) * (sig1 + sig2 + C2);
        lsum += num / den;
    }

    // block reduction: wave shuffle then LDS
#pragma unroll
    for (int off = 32; off > 0; off >>= 1)
        lsum += __shfl_down(lsum, off, 64);
    if ((tid & 63) == 0) wred[tid >> 6] = lsum;
    __syncthreads();
    if (tid == 0) {
        float bs = wred[0] + wred[1] + wred[2] + wred[3];
        atomicAdd(acc, (double)bs);
    }
}

__global__ void ssim3d_finalize(const double* __restrict__ acc,
                                float* __restrict__ out)
{
    out[0] = 1.0f - (float)(acc[0] / COUNT);
}

static Weights make_weights()
{
    Weights W;
    double g[11];
    double s;

    // wz: n=5, sigma=0.7
    s = 0.0;
    for (int i = 0; i < 5; ++i) {
        double d = i - 2;
        g[i] = exp(-(d * d) / (2.0 * 0.7 * 0.7));
        s += g[i];
    }
    for (int i = 0; i < 5; ++i) W.wz[i] = (float)(g[i] / s);

    // wy: n=11, sigma=1.5
    s = 0.0;
    for (int i = 0; i < 11; ++i) {
        double d = i - 5;
        g[i] = exp(-(d * d) / (2.0 * 1.5 * 1.5));
        s += g[i];
    }
    for (int i = 0; i < 11; ++i) W.wy[i] = (float)(g[i] / s);

    // wx: same as wy
    for (int i = 0; i < 11; ++i) W.wx[i] = W.wy[i];

    return W;
}

extern "C" void kernel_launch(void* const* d_in, const int* in_sizes, int n_in,
                              void* d_out, int out_size, void* d_ws, size_t ws_size,
                              hipStream_t stream)
{
    const float* img1 = (const float*)d_in[0];
    const float* img2 = (const float*)d_in[1];
    float* out = (float*)d_out;
    double* acc = (double*)d_ws;

    hipMemsetAsync(d_ws, 0, sizeof(double), stream);

    Weights W = make_weights();

    const int n_blocks = N_BATCH * DEPTH * (HEIGHT / TY) * (WIDTH / TX); // 16384
    ssim3d_fused<<<dim3(n_blocks), dim3(256), 0, stream>>>(img1, img2, acc, W);
    ssim3d_finalize<<<1, 1, 0, stream>>>(acc, out);
}

// Round 2
// 141.604 us; speedup vs baseline: 2.6287x; 2.6287x over previous
//
#include <hip/hip_runtime.h>
#include <math.h>

// Problem: SSIM3D on (8,1,32,256,256) f32, window (5,11,11) separable Gaussian.
#define N_BATCH 8
#define DEPTH   32
#define HEIGHT  256
#define WIDTH   256
#define HW      (HEIGHT*WIDTH)
#define WZ 5
#define WT 11

#define TY 32
#define TX 32
#define HYN 42            // TY + 10
#define HXN 42            // TX + 10
#define LST 44            // padded LDS row stride (floats) for b128 alignment
#define NPOS (HYN*HXN)    // 1764

#define COUNT 16777216.0  // 8*32*256*256
#define NACC 64

struct Weights { float wz[WZ]; float wy[WT]; float wx[WT]; };

__global__ __launch_bounds__(256) void ssim3d_fused(
    const float* __restrict__ img1, const float* __restrict__ img2,
    double* __restrict__ acc, Weights W)
{
    // Single LDS buffer, reused: stage2 holds z-conv fields over the 42x42 halo;
    // stage3 overwrites rows 0..31 with y-conv results. 5*42*44*4 = 36960 B.
    __shared__ __align__(16) float smem[5][HYN * LST];
    __shared__ float wred[4];

    // XCD-aware swizzle: 16384 blocks, 8 XCDs -> each XCD walks one batch n
    // in z-order so its 5-slice window (2.6 MB) lives in its private L2.
    int bid = blockIdx.x;
    bid = (bid & 7) * 2048 + (bid >> 3);

    const int txi   = bid & 7;
    const int tyi   = (bid >> 3) & 7;
    const int z_out = (bid >> 6) & 31;
    const int n     = bid >> 11;

    const int y0 = tyi * TY - 5;
    const int x0 = txi * TX - 5;
    const int tid = threadIdx.x;

    // ---- stage 0: per-position setup (hoisted out of the kz loop)
    int voff[7], lofs[7];
#pragma unroll
    for (int pi = 0; pi < 7; ++pi) {
        int pos = tid + pi * 256;
        int hy = pos / HXN;
        int hx = pos - hy * HXN;
        int gy = y0 + hy, gx = x0 + hx;
        bool inpos = pos < NPOS;
        lofs[pi] = inpos ? hy * LST + hx : -1;
        bool ok = inpos && ((unsigned)gy < HEIGHT) && ((unsigned)gx < WIDTH);
        voff[pi] = ok ? gy * WIDTH + gx : -1;
    }

    // ---- stage 1: z-conv of the 5 fields into registers
    float zacc[7][5];
#pragma unroll
    for (int pi = 0; pi < 7; ++pi)
#pragma unroll
        for (int f = 0; f < 5; ++f) zacc[pi][f] = 0.f;

    const size_t nbase = (size_t)n * DEPTH * HW;
#pragma unroll
    for (int kz = 0; kz < WZ; ++kz) {
        int z_in = z_out + kz - 2;
        if (z_in < 0 || z_in >= DEPTH) continue;   // zero padding in z
        const float wzv = W.wz[kz];
        const float* p1 = img1 + nbase + (size_t)z_in * HW;
        const float* p2 = img2 + nbase + (size_t)z_in * HW;
#pragma unroll
        for (int pi = 0; pi < 7; ++pi) {
            int o = voff[pi];
            float a = 0.f, b = 0.f;
            if (o >= 0) { a = p1[o]; b = p2[o]; }
            float ta = wzv * a, tb = wzv * b;
            zacc[pi][0] += ta;
            zacc[pi][1] += tb;
            zacc[pi][2] = fmaf(ta, a, zacc[pi][2]);
            zacc[pi][3] = fmaf(tb, b, zacc[pi][3]);
            zacc[pi][4] = fmaf(ta, b, zacc[pi][4]);
        }
    }

    // ---- stage 2: registers -> LDS
#pragma unroll
    for (int pi = 0; pi < 7; ++pi) {
        int lo = lofs[pi];
        if (lo >= 0) {
#pragma unroll
            for (int f = 0; f < 5; ++f) smem[f][lo] = zacc[pi][f];
        }
    }
    __syncthreads();

    // ---- stage 3: y-conv into registers (3 rows x 2 cols per thread,
    //               13-row sliding window, float2 LDS reads)
    const int g  = tid / 21;        // row-group
    const int xp = tid - g * 21;    // column pair 0..20 -> x = 2*xp
    const bool act3 = (g < 11);     // 231 active threads cover 33 >= 32 rows
    float2 yout[3][5];
    if (act3) {
        const int rowbase = 3 * g;
#pragma unroll
        for (int f = 0; f < 5; ++f) {
            float2 w[13];
#pragma unroll
            for (int i = 0; i < 13; ++i) {
                int row = rowbase + i;
                row = row > 41 ? 41 : row;   // clamp; clamped value feeds only discarded y=32
                w[i] = *(const float2*)&smem[f][row * LST + 2 * xp];
            }
#pragma unroll
            for (int r = 0; r < 3; ++r) {
                float sx = 0.f, sy = 0.f;
#pragma unroll
                for (int j = 0; j < WT; ++j) {
                    float wv = W.wy[j];
                    sx = fmaf(wv, w[r + j].x, sx);
                    sy = fmaf(wv, w[r + j].y, sy);
                }
                yout[r][f] = make_float2(sx, sy);
            }
        }
    }
    __syncthreads();
    if (act3) {
        const int rowbase = 3 * g;
#pragma unroll
        for (int r = 0; r < 3; ++r) {
            int y = rowbase + r;
            if (y < TY) {
#pragma unroll
                for (int f = 0; f < 5; ++f)
                    *(float2*)&smem[f][y * LST + 2 * xp] = yout[r][f];
            }
        }
    }
    __syncthreads();

    // ---- stage 4: x-conv (4 consecutive outputs per thread, b128 reads) + SSIM
    const int yy = tid >> 3;
    const int xq = (tid & 7) << 2;
    float s[5][4];
#pragma unroll
    for (int f = 0; f < 5; ++f) {
        const float* rowp = &smem[f][yy * LST + xq];
        float4 q0 = *(const float4*)(rowp);
        float4 q1 = *(const float4*)(rowp + 4);
        float4 q2 = *(const float4*)(rowp + 8);
        float4 q3 = *(const float4*)(rowp + 12);
        float w[16] = {q0.x,q0.y,q0.z,q0.w, q1.x,q1.y,q1.z,q1.w,
                       q2.x,q2.y,q2.z,q2.w, q3.x,q3.y,q3.z,q3.w};
#pragma unroll
        for (int k = 0; k < 4; ++k) {
            float sv = 0.f;
#pragma unroll
            for (int j = 0; j < WT; ++j)
                sv = fmaf(W.wx[j], w[k + j], sv);
            s[f][k] = sv;
        }
    }

    float lsum = 0.f;
    const float C1 = 0.0001f;
    const float C2 = 0.0009f;
#pragma unroll
    for (int k = 0; k < 4; ++k) {
        float mu1 = s[0][k], mu2 = s[1][k];
        float mu1_sq = mu1 * mu1;
        float mu2_sq = mu2 * mu2;
        float mu1_mu2 = mu1 * mu2;
        float sig1 = s[2][k] - mu1_sq;
        float sig2 = s[3][k] - mu2_sq;
        float sig12 = s[4][k] - mu1_mu2;
        float num = (2.f * mu1_mu2 + C1) * (2.f * sig12 + C2);
        float den = (mu1_sq + mu2_sq + C1) * (sig1 + sig2 + C2);
        lsum += num / den;
    }

    // ---- block reduction + spread atomics over 64 slots
#pragma unroll
    for (int off = 32; off > 0; off >>= 1)
        lsum += __shfl_down(lsum, off, 64);
    if ((tid & 63) == 0) wred[tid >> 6] = lsum;
    __syncthreads();
    if (tid == 0) {
        float bs = wred[0] + wred[1] + wred[2] + wred[3];
        atomicAdd(&acc[blockIdx.x & (NACC - 1)], (double)bs);
    }
}

__global__ void ssim3d_finalize(const double* __restrict__ acc,
                                float* __restrict__ out)
{
    double s = 0.0;
    for (int i = 0; i < NACC; ++i) s += acc[i];
    out[0] = 1.0f - (float)(s / COUNT);
}

static Weights make_weights()
{
    Weights W;
    double g[11];
    double s;

    s = 0.0;
    for (int i = 0; i < 5; ++i) {
        double d = i - 2;
        g[i] = exp(-(d * d) / (2.0 * 0.7 * 0.7));
        s += g[i];
    }
    for (int i = 0; i < 5; ++i) W.wz[i] = (float)(g[i] / s);

    s = 0.0;
    for (int i = 0; i < 11; ++i) {
        double d = i - 5;
        g[i] = exp(-(d * d) / (2.0 * 1.5 * 1.5));
        s += g[i];
    }
    for (int i = 0; i < 11; ++i) W.wy[i] = (float)(g[i] / s);
    for (int i = 0; i < 11; ++i) W.wx[i] = W.wy[i];

    return W;
}

extern "C" void kernel_launch(void* const* d_in, const int* in_sizes, int n_in,
                              void* d_out, int out_size, void* d_ws, size_t ws_size,
                              hipStream_t stream)
{
    const float* img1 = (const float*)d_in[0];
    const float* img2 = (const float*)d_in[1];
    float* out = (float*)d_out;
    double* acc = (double*)d_ws;

    hipMemsetAsync(d_ws, 0, NACC * sizeof(double), stream);

    Weights W = make_weights();

    const int n_blocks = N_BATCH * DEPTH * (HEIGHT / TY) * (WIDTH / TX); // 16384
    ssim3d_fused<<<dim3(n_blocks), dim3(256), 0, stream>>>(img1, img2, acc, W);
    ssim3d_finalize<<<1, 1, 0, stream>>>(acc, out);
}